// Round 1
// baseline (4282.110 us; speedup 1.0000x reference)
//
#include <hip/hip_runtime.h>

#define D 128

// ---------------- degree / norm ----------------

__global__ void init_deg_kernel(float* __restrict__ deg, int n) {
    int i = blockIdx.x * blockDim.x + threadIdx.x;
    if (i < n) deg[i] = 1.0f;   // self-loop contributes 1
}

__global__ void count_deg_kernel(const int* __restrict__ dst, float* __restrict__ deg, int E) {
    int e = blockIdx.x * blockDim.x + threadIdx.x;
    if (e < E) atomicAdd(&deg[dst[e]], 1.0f);
}

__global__ void dinv_kernel(float* __restrict__ deg, int n) {
    int i = blockIdx.x * blockDim.x + threadIdx.x;
    if (i < n) deg[i] = rsqrtf(deg[i]);   // in-place: deg -> dinv
}

__global__ void norm_kernel(const int* __restrict__ src, const int* __restrict__ dst,
                            const float* __restrict__ dinv, float* __restrict__ norm, int E) {
    int e = blockIdx.x * blockDim.x + threadIdx.x;
    if (e < E) norm[e] = dinv[src[e]] * dinv[dst[e]];
}

// ---------------- GEMM: out[n,:] = h[n,:] @ W  (fp32 vector ALU) ----------------
// Block: 256 threads, 64 nodes. LDS: 64x128 h-tile (32 KB).
// Thread (cg = tid&31 -> 4 cols, ng = tid>>5 -> 8 nodes): 32 accumulators.

#define TM 64

__global__ __launch_bounds__(256) void gemm128_kernel(const float* __restrict__ h,
                                                      const float* __restrict__ W,
                                                      float* __restrict__ out, int n) {
    __shared__ float sh[TM * D];
    const int tid = threadIdx.x;
    const int nbase = blockIdx.x * TM;

    // stage h tile: 64*128 floats = 2048 float4, 8 per thread
#pragma unroll
    for (int i = 0; i < 8; ++i) {
        int fi = tid + i * 256;            // float4 index within tile
        int node = nbase + (fi >> 5);      // 32 float4 per row
        float4 v = make_float4(0.f, 0.f, 0.f, 0.f);
        if (node < n) v = *(const float4*)&h[(size_t)node * D + ((fi & 31) << 2)];
        *(float4*)&sh[fi << 2] = v;
    }
    __syncthreads();

    const int cg = tid & 31;
    const int c4 = cg << 2;
    const int ng = tid >> 5;               // 0..7 -> nodes ng*8 .. ng*8+7
    const float* shb = &sh[(ng * 8) * D];

    float4 acc[8];
#pragma unroll
    for (int j = 0; j < 8; ++j) acc[j] = make_float4(0.f, 0.f, 0.f, 0.f);

    const float* wp = W + c4;
#pragma unroll 4
    for (int k = 0; k < D; ++k) {
        float4 w = *(const float4*)(wp + (size_t)k * D);
#pragma unroll
        for (int j = 0; j < 8; ++j) {
            float hv = shb[j * D + k];
            acc[j].x = fmaf(hv, w.x, acc[j].x);
            acc[j].y = fmaf(hv, w.y, acc[j].y);
            acc[j].z = fmaf(hv, w.z, acc[j].z);
            acc[j].w = fmaf(hv, w.w, acc[j].w);
        }
    }

#pragma unroll
    for (int j = 0; j < 8; ++j) {
        int node = nbase + ng * 8 + j;
        if (node < n) *(float4*)&out[(size_t)node * D + c4] = acc[j];
    }
}

// ---------------- edge scatter: agg[dst] += hW[src] * norm ----------------
// one thread per (edge, 4 features): 32 threads/edge

__global__ __launch_bounds__(256) void scatter_edges_kernel(const int* __restrict__ src,
                                                            const int* __restrict__ dst,
                                                            const float* __restrict__ norm,
                                                            const float* __restrict__ hW,
                                                            float* __restrict__ agg, int E) {
    int idx = blockIdx.x * blockDim.x + threadIdx.x;
    int e = idx >> 5;
    if (e >= E) return;
    int f = (idx & 31) << 2;
    int s = src[e];
    int d = dst[e];
    float nm = norm[e];
    float4 v = *(const float4*)&hW[(size_t)s * D + f];
    float* o = &agg[(size_t)d * D + f];
    atomicAdd(o + 0, v.x * nm);
    atomicAdd(o + 1, v.y * nm);
    atomicAdd(o + 2, v.z * nm);
    atomicAdd(o + 3, v.w * nm);
}

// ---------------- finish: + self-loop + bias (+ relu | + residual) ----------------

__global__ __launch_bounds__(256) void finish_relu_kernel(float* __restrict__ agg,
                                                          const float* __restrict__ hW,
                                                          const float* __restrict__ dinv,
                                                          const float* __restrict__ b, int n) {
    int idx4 = blockIdx.x * blockDim.x + threadIdx.x;   // float4 granularity
    if (idx4 >= n * (D / 4)) return;
    int node = idx4 >> 5;
    int c4 = (idx4 & 31) << 2;
    float di = dinv[node];
    float sl = di * di;
    float4 a = *(const float4*)&agg[(size_t)idx4 * 4];
    float4 hv = *(const float4*)&hW[(size_t)idx4 * 4];
    float4 bv = *(const float4*)&b[c4];
    float4 r;
    r.x = fmaxf(a.x + hv.x * sl + bv.x, 0.f);
    r.y = fmaxf(a.y + hv.y * sl + bv.y, 0.f);
    r.z = fmaxf(a.z + hv.z * sl + bv.z, 0.f);
    r.w = fmaxf(a.w + hv.w * sl + bv.w, 0.f);
    *(float4*)&agg[(size_t)idx4 * 4] = r;               // in-place: agg becomes next h
}

__global__ __launch_bounds__(256) void finish_final_kernel(const float* __restrict__ agg,
                                                           const float* __restrict__ hW,
                                                           const float* __restrict__ dinv,
                                                           const float* __restrict__ b,
                                                           const float* __restrict__ x,
                                                           float* __restrict__ out, int n) {
    int idx4 = blockIdx.x * blockDim.x + threadIdx.x;
    if (idx4 >= n * (D / 4)) return;
    int node = idx4 >> 5;
    int c4 = (idx4 & 31) << 2;
    float di = dinv[node];
    float sl = di * di;
    float4 a = *(const float4*)&agg[(size_t)idx4 * 4];
    float4 hv = *(const float4*)&hW[(size_t)idx4 * 4];
    float4 bv = *(const float4*)&b[c4];
    float4 xv = *(const float4*)&x[(size_t)idx4 * 4];
    float4 r;
    r.x = a.x + hv.x * sl + bv.x + xv.x;
    r.y = a.y + hv.y * sl + bv.y + xv.y;
    r.z = a.z + hv.z * sl + bv.z + xv.z;
    r.w = a.w + hv.w * sl + bv.w + xv.w;
    *(float4*)&out[(size_t)idx4 * 4] = r;
}

// ---------------- launch ----------------

extern "C" void kernel_launch(void* const* d_in, const int* in_sizes, int n_in,
                              void* d_out, int out_size, void* d_ws, size_t ws_size,
                              hipStream_t stream) {
    const float* x  = (const float*)d_in[0];
    const int*   ei = (const int*)d_in[1];
    const float* Ws[3] = {(const float*)d_in[2], (const float*)d_in[4], (const float*)d_in[6]};
    const float* bs[3] = {(const float*)d_in[3], (const float*)d_in[5], (const float*)d_in[7]};
    float* out = (float*)d_out;

    const int N = in_sizes[0] / D;
    const int E = in_sizes[1] / 2;
    const int* src = ei;
    const int* dst = ei + E;

    float* ws   = (float*)d_ws;
    float* dinv = ws;                       // N floats (deg, then dinv in-place)
    float* norm = ws + N;                   // E floats
    float* A    = norm + E;                 // N*D floats (hW)
    float* B    = A + (size_t)N * D;        // N*D floats (agg / next h)

    // degree + norm (once; reused by all 3 layers)
    init_deg_kernel<<<(N + 255) / 256, 256, 0, stream>>>(dinv, N);
    count_deg_kernel<<<(E + 255) / 256, 256, 0, stream>>>(dst, dinv, E);
    dinv_kernel<<<(N + 255) / 256, 256, 0, stream>>>(dinv, N);
    norm_kernel<<<(E + 255) / 256, 256, 0, stream>>>(src, dst, dinv, norm, E);

    const float* h = x;
    const int scatter_blocks = (int)(((size_t)E * 32 + 255) / 256);
    const int nd4_blocks = (N * (D / 4) + 255) / 256;

    for (int l = 0; l < 3; ++l) {
        gemm128_kernel<<<(N + TM - 1) / TM, 256, 0, stream>>>(h, Ws[l], A, N);
        hipMemsetAsync(B, 0, (size_t)N * D * sizeof(float), stream);
        scatter_edges_kernel<<<scatter_blocks, 256, 0, stream>>>(src, dst, norm, A, B, E);
        if (l < 2) {
            finish_relu_kernel<<<nd4_blocks, 256, 0, stream>>>(B, A, dinv, bs[l], N);
        } else {
            finish_final_kernel<<<nd4_blocks, 256, 0, stream>>>(B, A, dinv, bs[l], x, out, N);
        }
        h = B;
    }
}

// Round 2
// 499.425 us; speedup vs baseline: 8.5741x; 8.5741x over previous
//
#include <hip/hip_runtime.h>

#define D 128

// ---------------- CSR build ----------------

__global__ void count_deg_kernel(const int* __restrict__ dst, int* __restrict__ ideg, int E) {
    int e = blockIdx.x * blockDim.x + threadIdx.x;
    if (e < E) atomicAdd(&ideg[dst[e]], 1);
}

// per node: dinv = rsqrt(in_deg + 1 self-loop); allocate CSR row via global counter
// (row order is irrelevant -- only contiguity per node matters, so no prefix scan needed)
__global__ void alloc_rows_kernel(const int* __restrict__ ideg, int* __restrict__ base,
                                  int* __restrict__ cursor, float* __restrict__ dinv,
                                  int* __restrict__ counter, int n) {
    int i = blockIdx.x * blockDim.x + threadIdx.x;
    if (i >= n) return;
    int d = ideg[i];
    dinv[i] = rsqrtf((float)d + 1.0f);
    int b = atomicAdd(counter, d);
    base[i] = b;
    cursor[i] = b;
}

__global__ void fill_csr_kernel(const int* __restrict__ src, const int* __restrict__ dst,
                                const float* __restrict__ dinv, int* __restrict__ cursor,
                                int* __restrict__ csr_src, float* __restrict__ csr_ns, int E) {
    int e = blockIdx.x * blockDim.x + threadIdx.x;
    if (e >= E) return;
    int s = src[e];
    int d = dst[e];
    int pos = atomicAdd(&cursor[d], 1);
    csr_src[pos] = s;
    csr_ns[pos] = dinv[s];          // dst factor dinv[d] applied once at gather end
}

// ---------------- GEMM: out[n,:] = h[n,:] @ W  (fp32 vector ALU) ----------------

#define TM 64

__global__ __launch_bounds__(256) void gemm128_kernel(const float* __restrict__ h,
                                                      const float* __restrict__ W,
                                                      float* __restrict__ out, int n) {
    __shared__ float sh[TM * D];
    const int tid = threadIdx.x;
    const int nbase = blockIdx.x * TM;

#pragma unroll
    for (int i = 0; i < 8; ++i) {
        int fi = tid + i * 256;
        int node = nbase + (fi >> 5);
        float4 v = make_float4(0.f, 0.f, 0.f, 0.f);
        if (node < n) v = *(const float4*)&h[(size_t)node * D + ((fi & 31) << 2)];
        *(float4*)&sh[fi << 2] = v;
    }
    __syncthreads();

    const int c4 = (tid & 31) << 2;
    const int ng = tid >> 5;
    const float* shb = &sh[(ng * 8) * D];

    float4 acc[8];
#pragma unroll
    for (int j = 0; j < 8; ++j) acc[j] = make_float4(0.f, 0.f, 0.f, 0.f);

    const float* wp = W + c4;
#pragma unroll 4
    for (int k = 0; k < D; ++k) {
        float4 w = *(const float4*)(wp + (size_t)k * D);
#pragma unroll
        for (int j = 0; j < 8; ++j) {
            float hv = shb[j * D + k];
            acc[j].x = fmaf(hv, w.x, acc[j].x);
            acc[j].y = fmaf(hv, w.y, acc[j].y);
            acc[j].z = fmaf(hv, w.z, acc[j].z);
            acc[j].w = fmaf(hv, w.w, acc[j].w);
        }
    }

#pragma unroll
    for (int j = 0; j < 8; ++j) {
        int node = nbase + ng * 8 + j;
        if (node < n) *(float4*)&out[(size_t)node * D + c4] = acc[j];
    }
}

// ---------------- pull-side aggregation, fused epilogue ----------------
// 32 threads per dst node (4 floats each). acc = sum_e dinv[s]*hW[s] + dinv[d]*hW[d];
// out = acc*dinv[d] + bias, then relu (inner layers) or +x residual (last layer).

__global__ __launch_bounds__(256) void gather_kernel(const int* __restrict__ base,
                                                     const int* __restrict__ ideg,
                                                     const int* __restrict__ csr_src,
                                                     const float* __restrict__ csr_ns,
                                                     const float* __restrict__ hW,
                                                     const float* __restrict__ dinv,
                                                     const float* __restrict__ b,
                                                     const float* __restrict__ x,
                                                     float* __restrict__ out,
                                                     int n, int final_layer) {
    int node = blockIdx.x * 8 + (threadIdx.x >> 5);
    if (node >= n) return;
    const int f = (threadIdx.x & 31) << 2;
    const int start = base[node];
    const int len = ideg[node];

    float4 acc = make_float4(0.f, 0.f, 0.f, 0.f);
    for (int k = 0; k < len; ++k) {
        int s = csr_src[start + k];
        float ns = csr_ns[start + k];
        float4 v = *(const float4*)&hW[(size_t)s * D + f];
        acc.x = fmaf(v.x, ns, acc.x);
        acc.y = fmaf(v.y, ns, acc.y);
        acc.z = fmaf(v.z, ns, acc.z);
        acc.w = fmaf(v.w, ns, acc.w);
    }

    float di = dinv[node];
    float4 hv = *(const float4*)&hW[(size_t)node * D + f];
    acc.x = fmaf(hv.x, di, acc.x);
    acc.y = fmaf(hv.y, di, acc.y);
    acc.z = fmaf(hv.z, di, acc.z);
    acc.w = fmaf(hv.w, di, acc.w);

    float4 bv = *(const float4*)&b[f];
    float4 r;
    r.x = fmaf(acc.x, di, bv.x);
    r.y = fmaf(acc.y, di, bv.y);
    r.z = fmaf(acc.z, di, bv.z);
    r.w = fmaf(acc.w, di, bv.w);

    if (final_layer) {
        float4 xv = *(const float4*)&x[(size_t)node * D + f];
        r.x += xv.x; r.y += xv.y; r.z += xv.z; r.w += xv.w;
    } else {
        r.x = fmaxf(r.x, 0.f);
        r.y = fmaxf(r.y, 0.f);
        r.z = fmaxf(r.z, 0.f);
        r.w = fmaxf(r.w, 0.f);
    }
    *(float4*)&out[(size_t)node * D + f] = r;
}

// ---------------- launch ----------------

extern "C" void kernel_launch(void* const* d_in, const int* in_sizes, int n_in,
                              void* d_out, int out_size, void* d_ws, size_t ws_size,
                              hipStream_t stream) {
    const float* x  = (const float*)d_in[0];
    const int*   ei = (const int*)d_in[1];
    const float* Ws[3] = {(const float*)d_in[2], (const float*)d_in[4], (const float*)d_in[6]};
    const float* bs[3] = {(const float*)d_in[3], (const float*)d_in[5], (const float*)d_in[7]};
    float* out = (float*)d_out;

    const int N = in_sizes[0] / D;
    const int E = in_sizes[1] / 2;
    const int* src = ei;
    const int* dst = ei + E;

    // workspace layout
    int* ideg    = (int*)d_ws;              // N
    int* counter = ideg + N;                // 1
    int* base    = counter + 1;             // N
    int* cursor  = base + N;                // N
    int* csr_src = cursor + N;              // E
    float* dinv    = (float*)(csr_src + E); // N
    float* csr_ns  = dinv + N;              // E
    float* A       = csr_ns + E;            // N*D  (hW)
    float* B       = A + (size_t)N * D;     // N*D  (next h)

    // CSR build (once; reused by all 3 layers)
    hipMemsetAsync(ideg, 0, (size_t)(N + 1) * sizeof(int), stream);   // ideg + counter
    count_deg_kernel<<<(E + 255) / 256, 256, 0, stream>>>(dst, ideg, E);
    alloc_rows_kernel<<<(N + 255) / 256, 256, 0, stream>>>(ideg, base, cursor, dinv, counter, N);
    fill_csr_kernel<<<(E + 255) / 256, 256, 0, stream>>>(src, dst, dinv, cursor, csr_src, csr_ns, E);

    const int gather_blocks = (N + 7) / 8;
    const float* h = x;
    for (int l = 0; l < 3; ++l) {
        gemm128_kernel<<<(N + TM - 1) / TM, 256, 0, stream>>>(h, Ws[l], A, N);
        float* dest = (l == 2) ? out : B;
        gather_kernel<<<gather_blocks, 256, 0, stream>>>(base, ideg, csr_src, csr_ns, A,
                                                         dinv, bs[l], x, dest, N, l == 2);
        h = B;
    }
}

// Round 3
// 479.788 us; speedup vs baseline: 8.9250x; 1.0409x over previous
//
#include <hip/hip_runtime.h>

#define D 128

// ---------------- CSR build ----------------

__global__ void count_deg_kernel(const int* __restrict__ dst, int* __restrict__ ideg, int E) {
    int e = blockIdx.x * blockDim.x + threadIdx.x;
    if (e < E) atomicAdd(&ideg[dst[e]], 1);
}

// per node: dinv = rsqrt(in_deg + 1); allocate CSR row (padded to multiple of 4 for
// int4-aligned gather) via global counter -- row order irrelevant, no scan needed.
__global__ void alloc_rows_kernel(const int* __restrict__ ideg, int* __restrict__ base,
                                  int* __restrict__ cursor, float* __restrict__ dinv,
                                  int* __restrict__ counter, int n) {
    int i = blockIdx.x * blockDim.x + threadIdx.x;
    if (i >= n) return;
    int d = ideg[i];
    dinv[i] = rsqrtf((float)d + 1.0f);
    int pad = (d + 3) & ~3;
    int b = atomicAdd(counter, pad);
    base[i] = b;
    cursor[i] = b;
}

__global__ void fill_csr_kernel(const int* __restrict__ src, const int* __restrict__ dst,
                                const float* __restrict__ dinv, int* __restrict__ cursor,
                                int* __restrict__ csr_src, float* __restrict__ csr_ns, int E) {
    int e = blockIdx.x * blockDim.x + threadIdx.x;
    if (e >= E) return;
    int s = src[e];
    int d = dst[e];
    int pos = atomicAdd(&cursor[d], 1);
    csr_src[pos] = s;
    csr_ns[pos] = dinv[s];          // dst factor dinv[d] applied once at gather end
}

// ---------------- GEMM: out[n,:] = h[n,:] @ W  (fp32 vector ALU) ----------------
// 256 thr, 64 nodes/block. h-tile in LDS (32 KB). Thread: 8 nodes x 4 cols.
// k-chunks of 4: ds_read_b128 per node per chunk, 4 W float4 rows hoisted.

#define TM 64

__global__ __launch_bounds__(256) void gemm128_kernel(const float* __restrict__ h,
                                                      const float* __restrict__ W,
                                                      float* __restrict__ out, int n) {
    __shared__ float sh[TM * D];
    const int tid = threadIdx.x;
    const int nbase = blockIdx.x * TM;

#pragma unroll
    for (int i = 0; i < 8; ++i) {
        int fi = tid + i * 256;
        int node = nbase + (fi >> 5);
        float4 v = make_float4(0.f, 0.f, 0.f, 0.f);
        if (node < n) v = *(const float4*)&h[(size_t)node * D + ((fi & 31) << 2)];
        *(float4*)&sh[fi << 2] = v;
    }
    __syncthreads();

    const int c4 = (tid & 31) << 2;
    const int ng = tid >> 5;
    const float* shb = &sh[(ng * 8) * D];

    float4 acc[8];
#pragma unroll
    for (int j = 0; j < 8; ++j) acc[j] = make_float4(0.f, 0.f, 0.f, 0.f);

    for (int k = 0; k < D; k += 4) {
        float4 w0 = *(const float4*)&W[(size_t)(k + 0) * D + c4];
        float4 w1 = *(const float4*)&W[(size_t)(k + 1) * D + c4];
        float4 w2 = *(const float4*)&W[(size_t)(k + 2) * D + c4];
        float4 w3 = *(const float4*)&W[(size_t)(k + 3) * D + c4];
#pragma unroll
        for (int j = 0; j < 8; ++j) {
            float4 hv = *(const float4*)&shb[j * D + k];   // ds_read_b128
            acc[j].x = fmaf(hv.x, w0.x, acc[j].x); acc[j].y = fmaf(hv.x, w0.y, acc[j].y);
            acc[j].z = fmaf(hv.x, w0.z, acc[j].z); acc[j].w = fmaf(hv.x, w0.w, acc[j].w);
            acc[j].x = fmaf(hv.y, w1.x, acc[j].x); acc[j].y = fmaf(hv.y, w1.y, acc[j].y);
            acc[j].z = fmaf(hv.y, w1.z, acc[j].z); acc[j].w = fmaf(hv.y, w1.w, acc[j].w);
            acc[j].x = fmaf(hv.z, w2.x, acc[j].x); acc[j].y = fmaf(hv.z, w2.y, acc[j].y);
            acc[j].z = fmaf(hv.z, w2.z, acc[j].z); acc[j].w = fmaf(hv.z, w2.w, acc[j].w);
            acc[j].x = fmaf(hv.w, w3.x, acc[j].x); acc[j].y = fmaf(hv.w, w3.y, acc[j].y);
            acc[j].z = fmaf(hv.w, w3.z, acc[j].z); acc[j].w = fmaf(hv.w, w3.w, acc[j].w);
        }
    }

#pragma unroll
    for (int j = 0; j < 8; ++j) {
        int node = nbase + ng * 8 + j;
        if (node < n) *(float4*)&out[(size_t)node * D + c4] = acc[j];
    }
}

// ---------------- pull-side aggregation, fused epilogue ----------------
// 32 threads per dst node (float4/lane). Edge loop unrolled x4 (int4/float4 index
// loads, 4 independent row fetches, 2 acc chains) for memory-level parallelism.

__global__ __launch_bounds__(256) void gather_kernel(const int* __restrict__ base,
                                                     const int* __restrict__ ideg,
                                                     const int* __restrict__ csr_src,
                                                     const float* __restrict__ csr_ns,
                                                     const float* __restrict__ hW,
                                                     const float* __restrict__ dinv,
                                                     const float* __restrict__ b,
                                                     const float* __restrict__ x,
                                                     float* __restrict__ out,
                                                     int n, int final_layer) {
    int node = blockIdx.x * 8 + (threadIdx.x >> 5);
    if (node >= n) return;
    const int f = (threadIdx.x & 31) << 2;
    const int start = base[node];       // multiple of 4
    const int len = ideg[node];
    const int len4 = len & ~3;

    float4 acc0 = make_float4(0.f, 0.f, 0.f, 0.f);
    float4 acc1 = make_float4(0.f, 0.f, 0.f, 0.f);
    int k = 0;
    for (; k < len4; k += 4) {
        int4   s4 = *(const int4*)&csr_src[start + k];
        float4 n4 = *(const float4*)&csr_ns[start + k];
        float4 v0 = *(const float4*)&hW[(size_t)s4.x * D + f];
        float4 v1 = *(const float4*)&hW[(size_t)s4.y * D + f];
        float4 v2 = *(const float4*)&hW[(size_t)s4.z * D + f];
        float4 v3 = *(const float4*)&hW[(size_t)s4.w * D + f];
        acc0.x = fmaf(v0.x, n4.x, acc0.x); acc0.y = fmaf(v0.y, n4.x, acc0.y);
        acc0.z = fmaf(v0.z, n4.x, acc0.z); acc0.w = fmaf(v0.w, n4.x, acc0.w);
        acc1.x = fmaf(v1.x, n4.y, acc1.x); acc1.y = fmaf(v1.y, n4.y, acc1.y);
        acc1.z = fmaf(v1.z, n4.y, acc1.z); acc1.w = fmaf(v1.w, n4.y, acc1.w);
        acc0.x = fmaf(v2.x, n4.z, acc0.x); acc0.y = fmaf(v2.y, n4.z, acc0.y);
        acc0.z = fmaf(v2.z, n4.z, acc0.z); acc0.w = fmaf(v2.w, n4.z, acc0.w);
        acc1.x = fmaf(v3.x, n4.w, acc1.x); acc1.y = fmaf(v3.y, n4.w, acc1.y);
        acc1.z = fmaf(v3.z, n4.w, acc1.z); acc1.w = fmaf(v3.w, n4.w, acc1.w);
    }
    for (; k < len; ++k) {
        int s = csr_src[start + k];
        float ns = csr_ns[start + k];
        float4 v = *(const float4*)&hW[(size_t)s * D + f];
        acc0.x = fmaf(v.x, ns, acc0.x); acc0.y = fmaf(v.y, ns, acc0.y);
        acc0.z = fmaf(v.z, ns, acc0.z); acc0.w = fmaf(v.w, ns, acc0.w);
    }

    float di = dinv[node];
    float4 hv = *(const float4*)&hW[(size_t)node * D + f];
    float4 acc;
    acc.x = fmaf(hv.x, di, acc0.x + acc1.x);
    acc.y = fmaf(hv.y, di, acc0.y + acc1.y);
    acc.z = fmaf(hv.z, di, acc0.z + acc1.z);
    acc.w = fmaf(hv.w, di, acc0.w + acc1.w);

    float4 bv = *(const float4*)&b[f];
    float4 r;
    r.x = fmaf(acc.x, di, bv.x);
    r.y = fmaf(acc.y, di, bv.y);
    r.z = fmaf(acc.z, di, bv.z);
    r.w = fmaf(acc.w, di, bv.w);

    if (final_layer) {
        float4 xv = *(const float4*)&x[(size_t)node * D + f];
        r.x += xv.x; r.y += xv.y; r.z += xv.z; r.w += xv.w;
    } else {
        r.x = fmaxf(r.x, 0.f);
        r.y = fmaxf(r.y, 0.f);
        r.z = fmaxf(r.z, 0.f);
        r.w = fmaxf(r.w, 0.f);
    }
    *(float4*)&out[(size_t)node * D + f] = r;
}

// ---------------- launch ----------------

extern "C" void kernel_launch(void* const* d_in, const int* in_sizes, int n_in,
                              void* d_out, int out_size, void* d_ws, size_t ws_size,
                              hipStream_t stream) {
    const float* x  = (const float*)d_in[0];
    const int*   ei = (const int*)d_in[1];
    const float* Ws[3] = {(const float*)d_in[2], (const float*)d_in[4], (const float*)d_in[6]};
    const float* bs[3] = {(const float*)d_in[3], (const float*)d_in[5], (const float*)d_in[7]};
    float* out = (float*)d_out;

    const int N = in_sizes[0] / D;
    const int E = in_sizes[1] / 2;
    const int* src = ei;
    const int* dst = ei + E;

    // workspace layout (all offsets multiples of 4 elements -> 16B aligned)
    const size_t Na = ((size_t)N + 3) & ~(size_t)3;        // 50000 (already x4)
    const size_t Ecap = ((size_t)E + 3 * (size_t)N + 3) & ~(size_t)3;  // padded CSR capacity
    int* ideg    = (int*)d_ws;                  // Na
    int* base    = ideg + Na;                   // Na
    int* cursor  = base + Na;                   // Na
    int* counter = cursor + Na;                 // 4 (1 used)
    int* csr_src = counter + 4;                 // Ecap
    float* csr_ns = (float*)(csr_src + Ecap);   // Ecap
    float* dinv   = csr_ns + Ecap;              // Na
    float* A      = dinv + Na;                  // N*D  (hW)
    float* B      = A + (size_t)N * D;          // N*D  (next h)

    // CSR build (once; reused by all 3 layers)
    hipMemsetAsync(ideg, 0, Na * sizeof(int), stream);
    hipMemsetAsync(counter, 0, sizeof(int), stream);
    count_deg_kernel<<<(E + 255) / 256, 256, 0, stream>>>(dst, ideg, E);
    alloc_rows_kernel<<<(N + 255) / 256, 256, 0, stream>>>(ideg, base, cursor, dinv, counter, N);
    fill_csr_kernel<<<(E + 255) / 256, 256, 0, stream>>>(src, dst, dinv, cursor, csr_src, csr_ns, E);

    const int gather_blocks = (N + 7) / 8;
    const float* h = x;
    for (int l = 0; l < 3; ++l) {
        gemm128_kernel<<<(N + TM - 1) / TM, 256, 0, stream>>>(h, Ws[l], A, N);
        float* dest = (l == 2) ? out : B;
        gather_kernel<<<gather_blocks, 256, 0, stream>>>(base, ideg, csr_src, csr_ns, A,
                                                         dinv, bs[l], x, dest, N, l == 2);
        h = B;
    }
}

// Round 4
// 392.361 us; speedup vs baseline: 10.9137x; 1.2228x over previous
//
#include <hip/hip_runtime.h>
#include <hip/hip_bf16.h>

#define D 128

// ---------------- helpers ----------------

__device__ __forceinline__ unsigned short f2bf_rtne(float f) {
    unsigned int u = __float_as_uint(f);
    u += 0x7fffu + ((u >> 16) & 1u);          // round-to-nearest-even
    return (unsigned short)(u >> 16);
}

// decode uint32 holding two bf16 (low = even col, high = odd col)
__device__ __forceinline__ float bf_lo(unsigned int u) { return __uint_as_float(u << 16); }
__device__ __forceinline__ float bf_hi(unsigned int u) { return __uint_as_float(u & 0xffff0000u); }

// ---------------- CSR build ----------------

__global__ void count_deg_kernel(const int* __restrict__ dst, int* __restrict__ ideg, int E) {
    int e = blockIdx.x * blockDim.x + threadIdx.x;
    if (e < E) atomicAdd(&ideg[dst[e]], 1);
}

// per node: dinv = rsqrt(in_deg + 1); allocate CSR row (padded to x4) via
// wave-prefix-scan + ONE atomic per wave (50000 same-address atomics serialized
// device-wide was a hidden cost).
__global__ void alloc_rows_kernel(const int* __restrict__ ideg, int* __restrict__ base,
                                  int* __restrict__ cursor, float* __restrict__ dinv,
                                  int* __restrict__ counter, int n) {
    int i = blockIdx.x * blockDim.x + threadIdx.x;
    int lane = threadIdx.x & 63;
    int d = (i < n) ? ideg[i] : 0;
    int pad = (d + 3) & ~3;
    int scan = pad;                            // inclusive scan over the wave
#pragma unroll
    for (int off = 1; off < 64; off <<= 1) {
        int v = __shfl_up(scan, off);
        if (lane >= off) scan += v;
    }
    int total = __shfl(scan, 63);
    int wbase = 0;
    if (lane == 63) wbase = atomicAdd(counter, total);
    wbase = __shfl(wbase, 63);
    int b = wbase + scan - pad;                // exclusive position
    if (i < n) {
        dinv[i] = rsqrtf((float)d + 1.0f);
        base[i] = b;
        cursor[i] = b;
    }
}

__global__ void fill_csr_kernel(const int* __restrict__ src, const int* __restrict__ dst,
                                const float* __restrict__ dinv, int* __restrict__ cursor,
                                int* __restrict__ csr_src, float* __restrict__ csr_ns, int E) {
    int e = blockIdx.x * blockDim.x + threadIdx.x;
    if (e >= E) return;
    int s = src[e];
    int d = dst[e];
    int pos = atomicAdd(&cursor[d], 1);
    csr_src[pos] = s;
    csr_ns[pos] = dinv[s];          // dst factor dinv[d] applied once at gather end
}

// ---------------- GEMM: out[n,:] = bf16(h[n,:] @ W)  (fp32 vector ALU) ----------------
// 256 thr, 64 nodes/block. h-tile in LDS. Thread: 8 nodes x 4 cols. bf16 epilogue.

#define TM 64

__global__ __launch_bounds__(256) void gemm128_kernel(const float* __restrict__ h,
                                                      const float* __restrict__ W,
                                                      unsigned short* __restrict__ out, int n) {
    __shared__ float sh[TM * D];
    const int tid = threadIdx.x;
    const int nbase = blockIdx.x * TM;

#pragma unroll
    for (int i = 0; i < 8; ++i) {
        int fi = tid + i * 256;
        int node = nbase + (fi >> 5);
        float4 v = make_float4(0.f, 0.f, 0.f, 0.f);
        if (node < n) v = *(const float4*)&h[(size_t)node * D + ((fi & 31) << 2)];
        *(float4*)&sh[fi << 2] = v;
    }
    __syncthreads();

    const int c4 = (tid & 31) << 2;
    const int ng = tid >> 5;
    const float* shb = &sh[(ng * 8) * D];

    float4 acc[8];
#pragma unroll
    for (int j = 0; j < 8; ++j) acc[j] = make_float4(0.f, 0.f, 0.f, 0.f);

    for (int k = 0; k < D; k += 4) {
        float4 w0 = *(const float4*)&W[(size_t)(k + 0) * D + c4];
        float4 w1 = *(const float4*)&W[(size_t)(k + 1) * D + c4];
        float4 w2 = *(const float4*)&W[(size_t)(k + 2) * D + c4];
        float4 w3 = *(const float4*)&W[(size_t)(k + 3) * D + c4];
#pragma unroll
        for (int j = 0; j < 8; ++j) {
            float4 hv = *(const float4*)&shb[j * D + k];   // ds_read_b128
            acc[j].x = fmaf(hv.x, w0.x, acc[j].x); acc[j].y = fmaf(hv.x, w0.y, acc[j].y);
            acc[j].z = fmaf(hv.x, w0.z, acc[j].z); acc[j].w = fmaf(hv.x, w0.w, acc[j].w);
            acc[j].x = fmaf(hv.y, w1.x, acc[j].x); acc[j].y = fmaf(hv.y, w1.y, acc[j].y);
            acc[j].z = fmaf(hv.y, w1.z, acc[j].z); acc[j].w = fmaf(hv.y, w1.w, acc[j].w);
            acc[j].x = fmaf(hv.z, w2.x, acc[j].x); acc[j].y = fmaf(hv.z, w2.y, acc[j].y);
            acc[j].z = fmaf(hv.z, w2.z, acc[j].z); acc[j].w = fmaf(hv.z, w2.w, acc[j].w);
            acc[j].x = fmaf(hv.w, w3.x, acc[j].x); acc[j].y = fmaf(hv.w, w3.y, acc[j].y);
            acc[j].z = fmaf(hv.w, w3.z, acc[j].z); acc[j].w = fmaf(hv.w, w3.w, acc[j].w);
        }
    }

#pragma unroll
    for (int j = 0; j < 8; ++j) {
        int node = nbase + ng * 8 + j;
        if (node < n) {
            ushort4 p;
            p.x = f2bf_rtne(acc[j].x);
            p.y = f2bf_rtne(acc[j].y);
            p.z = f2bf_rtne(acc[j].z);
            p.w = f2bf_rtne(acc[j].w);
            *(ushort4*)&out[(size_t)node * D + c4] = p;    // 8B store
        }
    }
}

// ---------------- pull-side aggregation (bf16 rows), fused epilogue ----------------
// 32 threads per dst node, 4 features/lane (uint2 = 4 bf16 = 8B, 256B/row coalesced).
// Edge loop unrolled x4: 4 independent row fetches in flight.

__global__ __launch_bounds__(256) void gather_kernel(const int* __restrict__ base,
                                                     const int* __restrict__ ideg,
                                                     const int* __restrict__ csr_src,
                                                     const float* __restrict__ csr_ns,
                                                     const unsigned short* __restrict__ hW,
                                                     const float* __restrict__ dinv,
                                                     const float* __restrict__ b,
                                                     const float* __restrict__ x,
                                                     float* __restrict__ out,
                                                     int n, int final_layer) {
    int node = blockIdx.x * 8 + (threadIdx.x >> 5);
    if (node >= n) return;
    const int f = (threadIdx.x & 31) << 2;
    const int start = base[node];       // multiple of 4
    const int len = ideg[node];
    const int len4 = len & ~3;

    float4 acc0 = make_float4(0.f, 0.f, 0.f, 0.f);
    float4 acc1 = make_float4(0.f, 0.f, 0.f, 0.f);
    int k = 0;
    for (; k < len4; k += 4) {
        int4   s4 = *(const int4*)&csr_src[start + k];
        float4 n4 = *(const float4*)&csr_ns[start + k];
        uint2 u0 = *(const uint2*)&hW[(size_t)s4.x * D + f];
        uint2 u1 = *(const uint2*)&hW[(size_t)s4.y * D + f];
        uint2 u2 = *(const uint2*)&hW[(size_t)s4.z * D + f];
        uint2 u3 = *(const uint2*)&hW[(size_t)s4.w * D + f];
        acc0.x = fmaf(bf_lo(u0.x), n4.x, acc0.x); acc0.y = fmaf(bf_hi(u0.x), n4.x, acc0.y);
        acc0.z = fmaf(bf_lo(u0.y), n4.x, acc0.z); acc0.w = fmaf(bf_hi(u0.y), n4.x, acc0.w);
        acc1.x = fmaf(bf_lo(u1.x), n4.y, acc1.x); acc1.y = fmaf(bf_hi(u1.x), n4.y, acc1.y);
        acc1.z = fmaf(bf_lo(u1.y), n4.y, acc1.z); acc1.w = fmaf(bf_hi(u1.y), n4.y, acc1.w);
        acc0.x = fmaf(bf_lo(u2.x), n4.z, acc0.x); acc0.y = fmaf(bf_hi(u2.x), n4.z, acc0.y);
        acc0.z = fmaf(bf_lo(u2.y), n4.z, acc0.z); acc0.w = fmaf(bf_hi(u2.y), n4.z, acc0.w);
        acc1.x = fmaf(bf_lo(u3.x), n4.w, acc1.x); acc1.y = fmaf(bf_hi(u3.x), n4.w, acc1.y);
        acc1.z = fmaf(bf_lo(u3.y), n4.w, acc1.z); acc1.w = fmaf(bf_hi(u3.y), n4.w, acc1.w);
    }
    for (; k < len; ++k) {
        int s = csr_src[start + k];
        float ns = csr_ns[start + k];
        uint2 u = *(const uint2*)&hW[(size_t)s * D + f];
        acc0.x = fmaf(bf_lo(u.x), ns, acc0.x); acc0.y = fmaf(bf_hi(u.x), ns, acc0.y);
        acc0.z = fmaf(bf_lo(u.y), ns, acc0.z); acc0.w = fmaf(bf_hi(u.y), ns, acc0.w);
    }

    float di = dinv[node];
    uint2 uh = *(const uint2*)&hW[(size_t)node * D + f];
    float4 acc;
    acc.x = fmaf(bf_lo(uh.x), di, acc0.x + acc1.x);
    acc.y = fmaf(bf_hi(uh.x), di, acc0.y + acc1.y);
    acc.z = fmaf(bf_lo(uh.y), di, acc0.z + acc1.z);
    acc.w = fmaf(bf_hi(uh.y), di, acc0.w + acc1.w);

    float4 bv = *(const float4*)&b[f];
    float4 r;
    r.x = fmaf(acc.x, di, bv.x);
    r.y = fmaf(acc.y, di, bv.y);
    r.z = fmaf(acc.z, di, bv.z);
    r.w = fmaf(acc.w, di, bv.w);

    if (final_layer) {
        float4 xv = *(const float4*)&x[(size_t)node * D + f];
        r.x += xv.x; r.y += xv.y; r.z += xv.z; r.w += xv.w;
    } else {
        r.x = fmaxf(r.x, 0.f);
        r.y = fmaxf(r.y, 0.f);
        r.z = fmaxf(r.z, 0.f);
        r.w = fmaxf(r.w, 0.f);
    }
    *(float4*)&out[(size_t)node * D + f] = r;
}

// ---------------- launch ----------------

extern "C" void kernel_launch(void* const* d_in, const int* in_sizes, int n_in,
                              void* d_out, int out_size, void* d_ws, size_t ws_size,
                              hipStream_t stream) {
    const float* x  = (const float*)d_in[0];
    const int*   ei = (const int*)d_in[1];
    const float* Ws[3] = {(const float*)d_in[2], (const float*)d_in[4], (const float*)d_in[6]};
    const float* bs[3] = {(const float*)d_in[3], (const float*)d_in[5], (const float*)d_in[7]};
    float* out = (float*)d_out;

    const int N = in_sizes[0] / D;
    const int E = in_sizes[1] / 2;
    const int* src = ei;
    const int* dst = ei + E;

    // workspace layout (all offsets multiples of 4 elements -> 16B aligned)
    const size_t Na = ((size_t)N + 3) & ~(size_t)3;
    const size_t Ecap = ((size_t)E + 3 * (size_t)N + 3) & ~(size_t)3;  // padded CSR capacity
    int* ideg    = (int*)d_ws;                  // Na
    int* base    = ideg + Na;                   // Na
    int* cursor  = base + Na;                   // Na
    int* counter = cursor + Na;                 // 4 (1 used)
    int* csr_src = counter + 4;                 // Ecap
    float* csr_ns = (float*)(csr_src + Ecap);   // Ecap
    float* dinv   = csr_ns + Ecap;              // Na
    unsigned short* A = (unsigned short*)(dinv + Na);        // N*D bf16 (hW)
    float* B = (float*)(A + (((size_t)N * D + 7) & ~(size_t)7)); // N*D fp32 (next h)

    // CSR build (once; reused by all 3 layers)
    hipMemsetAsync(ideg, 0, Na * sizeof(int), stream);
    hipMemsetAsync(counter, 0, sizeof(int), stream);
    count_deg_kernel<<<(E + 255) / 256, 256, 0, stream>>>(dst, ideg, E);
    alloc_rows_kernel<<<(N + 255) / 256, 256, 0, stream>>>(ideg, base, cursor, dinv, counter, N);
    fill_csr_kernel<<<(E + 255) / 256, 256, 0, stream>>>(src, dst, dinv, cursor, csr_src, csr_ns, E);

    const int gather_blocks = (N + 7) / 8;
    const float* h = x;
    for (int l = 0; l < 3; ++l) {
        gemm128_kernel<<<(N + TM - 1) / TM, 256, 0, stream>>>(h, Ws[l], A, N);
        float* dest = (l == 2) ? out : B;
        gather_kernel<<<gather_blocks, 256, 0, stream>>>(base, ideg, csr_src, csr_ns, A,
                                                         dinv, bs[l], x, dest, N, l == 2);
        h = B;
    }
}

// Round 5
// 342.965 us; speedup vs baseline: 12.4856x; 1.1440x over previous
//
#include <hip/hip_runtime.h>
#include <hip/hip_bf16.h>

#define D 128
#define BCAP 64          // bucket capacity per node (in-deg is Poisson(16); P(>64) ~ 1e-22)

// ---------------- helpers ----------------

__device__ __forceinline__ unsigned short f2bf_rtne(float f) {
    unsigned int u = __float_as_uint(f);
    u += 0x7fffu + ((u >> 16) & 1u);          // round-to-nearest-even
    return (unsigned short)(u >> 16);
}

__device__ __forceinline__ float bf_lo(unsigned int u) { return __uint_as_float(u << 16); }
__device__ __forceinline__ float bf_hi(unsigned int u) { return __uint_as_float(u & 0xffff0000u); }

// ---------------- single-pass bucketed CSR build ----------------
// cnt[d] counts in-degree AND serves as the insert cursor; bucket row d is the
// BCAP-slot contiguous region at d*BCAP. Row order is irrelevant for a sum.

__global__ void fill_bucket_kernel(const int* __restrict__ src, const int* __restrict__ dst,
                                   int* __restrict__ cnt, int* __restrict__ bucket, int E) {
    int e = blockIdx.x * blockDim.x + threadIdx.x;
    if (e >= E) return;
    int s = src[e];
    int d = dst[e];
    int pos = atomicAdd(&cnt[d], 1);
    if (pos < BCAP) bucket[((size_t)d << 6) + pos] = s;   // guard: memory-safe always
}

__global__ void dinv_kernel(const int* __restrict__ cnt, float* __restrict__ dinv, int n) {
    int i = blockIdx.x * blockDim.x + threadIdx.x;
    if (i < n) dinv[i] = rsqrtf((float)cnt[i] + 1.0f);    // +1 self-loop
}

// ---------------- GEMM: out[n,:] = bf16(h[n,:] @ W)  (fp32 vector ALU) ----------------

#define TM 64

__global__ __launch_bounds__(256) void gemm128_kernel(const float* __restrict__ h,
                                                      const float* __restrict__ W,
                                                      unsigned short* __restrict__ out, int n) {
    __shared__ float sh[TM * D];
    const int tid = threadIdx.x;
    const int nbase = blockIdx.x * TM;

#pragma unroll
    for (int i = 0; i < 8; ++i) {
        int fi = tid + i * 256;
        int node = nbase + (fi >> 5);
        float4 v = make_float4(0.f, 0.f, 0.f, 0.f);
        if (node < n) v = *(const float4*)&h[(size_t)node * D + ((fi & 31) << 2)];
        *(float4*)&sh[fi << 2] = v;
    }
    __syncthreads();

    const int c4 = (tid & 31) << 2;
    const int ng = tid >> 5;
    const float* shb = &sh[(ng * 8) * D];

    float4 acc[8];
#pragma unroll
    for (int j = 0; j < 8; ++j) acc[j] = make_float4(0.f, 0.f, 0.f, 0.f);

    for (int k = 0; k < D; k += 4) {
        float4 w0 = *(const float4*)&W[(size_t)(k + 0) * D + c4];
        float4 w1 = *(const float4*)&W[(size_t)(k + 1) * D + c4];
        float4 w2 = *(const float4*)&W[(size_t)(k + 2) * D + c4];
        float4 w3 = *(const float4*)&W[(size_t)(k + 3) * D + c4];
#pragma unroll
        for (int j = 0; j < 8; ++j) {
            float4 hv = *(const float4*)&shb[j * D + k];   // ds_read_b128
            acc[j].x = fmaf(hv.x, w0.x, acc[j].x); acc[j].y = fmaf(hv.x, w0.y, acc[j].y);
            acc[j].z = fmaf(hv.x, w0.z, acc[j].z); acc[j].w = fmaf(hv.x, w0.w, acc[j].w);
            acc[j].x = fmaf(hv.y, w1.x, acc[j].x); acc[j].y = fmaf(hv.y, w1.y, acc[j].y);
            acc[j].z = fmaf(hv.y, w1.z, acc[j].z); acc[j].w = fmaf(hv.y, w1.w, acc[j].w);
            acc[j].x = fmaf(hv.z, w2.x, acc[j].x); acc[j].y = fmaf(hv.z, w2.y, acc[j].y);
            acc[j].z = fmaf(hv.z, w2.z, acc[j].z); acc[j].w = fmaf(hv.z, w2.w, acc[j].w);
            acc[j].x = fmaf(hv.w, w3.x, acc[j].x); acc[j].y = fmaf(hv.w, w3.y, acc[j].y);
            acc[j].z = fmaf(hv.w, w3.z, acc[j].z); acc[j].w = fmaf(hv.w, w3.w, acc[j].w);
        }
    }

#pragma unroll
    for (int j = 0; j < 8; ++j) {
        int node = nbase + ng * 8 + j;
        if (node < n) {
            ushort4 p;
            p.x = f2bf_rtne(acc[j].x);
            p.y = f2bf_rtne(acc[j].y);
            p.z = f2bf_rtne(acc[j].z);
            p.w = f2bf_rtne(acc[j].w);
            *(ushort4*)&out[(size_t)node * D + c4] = p;
        }
    }
}

// ---------------- pull-side aggregation (bf16 rows, bucket CSR), fused epilogue ----
// 32 threads per dst node, 4 features/lane. Edge loop unrolled x8; dinv[s] loaded
// inline (same addr across the 32 lanes -> broadcast, L2-resident 200 KB).

__global__ __launch_bounds__(256) void gather_kernel(const int* __restrict__ cnt,
                                                     const int* __restrict__ bucket,
                                                     const unsigned short* __restrict__ hW,
                                                     const float* __restrict__ dinv,
                                                     const float* __restrict__ b,
                                                     const float* __restrict__ x,
                                                     float* __restrict__ out,
                                                     int n, int final_layer) {
    int node = blockIdx.x * 8 + (threadIdx.x >> 5);
    if (node >= n) return;
    const int f = (threadIdx.x & 31) << 2;
    const int* row = bucket + ((size_t)node << 6);
    int len = cnt[node];
    if (len > BCAP) len = BCAP;
    const int len8 = len & ~7;

    float4 acc0 = make_float4(0.f, 0.f, 0.f, 0.f);
    float4 acc1 = make_float4(0.f, 0.f, 0.f, 0.f);
    int k = 0;
    for (; k < len8; k += 8) {
        int4 sa = *(const int4*)&row[k];
        int4 sb = *(const int4*)&row[k + 4];
        float n0 = dinv[sa.x], n1 = dinv[sa.y], n2 = dinv[sa.z], n3 = dinv[sa.w];
        float n4 = dinv[sb.x], n5 = dinv[sb.y], n6 = dinv[sb.z], n7 = dinv[sb.w];
        uint2 u0 = *(const uint2*)&hW[(size_t)sa.x * D + f];
        uint2 u1 = *(const uint2*)&hW[(size_t)sa.y * D + f];
        uint2 u2 = *(const uint2*)&hW[(size_t)sa.z * D + f];
        uint2 u3 = *(const uint2*)&hW[(size_t)sa.w * D + f];
        uint2 u4 = *(const uint2*)&hW[(size_t)sb.x * D + f];
        uint2 u5 = *(const uint2*)&hW[(size_t)sb.y * D + f];
        uint2 u6 = *(const uint2*)&hW[(size_t)sb.z * D + f];
        uint2 u7 = *(const uint2*)&hW[(size_t)sb.w * D + f];
        acc0.x = fmaf(bf_lo(u0.x), n0, acc0.x); acc0.y = fmaf(bf_hi(u0.x), n0, acc0.y);
        acc0.z = fmaf(bf_lo(u0.y), n0, acc0.z); acc0.w = fmaf(bf_hi(u0.y), n0, acc0.w);
        acc1.x = fmaf(bf_lo(u1.x), n1, acc1.x); acc1.y = fmaf(bf_hi(u1.x), n1, acc1.y);
        acc1.z = fmaf(bf_lo(u1.y), n1, acc1.z); acc1.w = fmaf(bf_hi(u1.y), n1, acc1.w);
        acc0.x = fmaf(bf_lo(u2.x), n2, acc0.x); acc0.y = fmaf(bf_hi(u2.x), n2, acc0.y);
        acc0.z = fmaf(bf_lo(u2.y), n2, acc0.z); acc0.w = fmaf(bf_hi(u2.y), n2, acc0.w);
        acc1.x = fmaf(bf_lo(u3.x), n3, acc1.x); acc1.y = fmaf(bf_hi(u3.x), n3, acc1.y);
        acc1.z = fmaf(bf_lo(u3.y), n3, acc1.z); acc1.w = fmaf(bf_hi(u3.y), n3, acc1.w);
        acc0.x = fmaf(bf_lo(u4.x), n4, acc0.x); acc0.y = fmaf(bf_hi(u4.x), n4, acc0.y);
        acc0.z = fmaf(bf_lo(u4.y), n4, acc0.z); acc0.w = fmaf(bf_hi(u4.y), n4, acc0.w);
        acc1.x = fmaf(bf_lo(u5.x), n5, acc1.x); acc1.y = fmaf(bf_hi(u5.x), n5, acc1.y);
        acc1.z = fmaf(bf_lo(u5.y), n5, acc1.z); acc1.w = fmaf(bf_hi(u5.y), n5, acc1.w);
        acc0.x = fmaf(bf_lo(u6.x), n6, acc0.x); acc0.y = fmaf(bf_hi(u6.x), n6, acc0.y);
        acc0.z = fmaf(bf_lo(u6.y), n6, acc0.z); acc0.w = fmaf(bf_hi(u6.y), n6, acc0.w);
        acc1.x = fmaf(bf_lo(u7.x), n7, acc1.x); acc1.y = fmaf(bf_hi(u7.x), n7, acc1.y);
        acc1.z = fmaf(bf_lo(u7.y), n7, acc1.z); acc1.w = fmaf(bf_hi(u7.y), n7, acc1.w);
    }
    for (; k < len; ++k) {
        int s = row[k];
        float ns = dinv[s];
        uint2 u = *(const uint2*)&hW[(size_t)s * D + f];
        acc0.x = fmaf(bf_lo(u.x), ns, acc0.x); acc0.y = fmaf(bf_hi(u.x), ns, acc0.y);
        acc0.z = fmaf(bf_lo(u.y), ns, acc0.z); acc0.w = fmaf(bf_hi(u.y), ns, acc0.w);
    }

    float di = dinv[node];
    uint2 uh = *(const uint2*)&hW[(size_t)node * D + f];
    float4 acc;
    acc.x = fmaf(bf_lo(uh.x), di, acc0.x + acc1.x);
    acc.y = fmaf(bf_hi(uh.x), di, acc0.y + acc1.y);
    acc.z = fmaf(bf_lo(uh.y), di, acc0.z + acc1.z);
    acc.w = fmaf(bf_hi(uh.y), di, acc0.w + acc1.w);

    float4 bv = *(const float4*)&b[f];
    float4 r;
    r.x = fmaf(acc.x, di, bv.x);
    r.y = fmaf(acc.y, di, bv.y);
    r.z = fmaf(acc.z, di, bv.z);
    r.w = fmaf(acc.w, di, bv.w);

    if (final_layer) {
        float4 xv = *(const float4*)&x[(size_t)node * D + f];
        r.x += xv.x; r.y += xv.y; r.z += xv.z; r.w += xv.w;
    } else {
        r.x = fmaxf(r.x, 0.f);
        r.y = fmaxf(r.y, 0.f);
        r.z = fmaxf(r.z, 0.f);
        r.w = fmaxf(r.w, 0.f);
    }
    *(float4*)&out[(size_t)node * D + f] = r;
}

// ---------------- launch ----------------

extern "C" void kernel_launch(void* const* d_in, const int* in_sizes, int n_in,
                              void* d_out, int out_size, void* d_ws, size_t ws_size,
                              hipStream_t stream) {
    const float* x  = (const float*)d_in[0];
    const int*   ei = (const int*)d_in[1];
    const float* Ws[3] = {(const float*)d_in[2], (const float*)d_in[4], (const float*)d_in[6]};
    const float* bs[3] = {(const float*)d_in[3], (const float*)d_in[5], (const float*)d_in[7]};
    float* out = (float*)d_out;

    const int N = in_sizes[0] / D;
    const int E = in_sizes[1] / 2;
    const int* src = ei;
    const int* dst = ei + E;

    // workspace layout (16B-aligned pieces)
    const size_t Na = ((size_t)N + 3) & ~(size_t)3;
    int*   cnt    = (int*)d_ws;                              // Na
    int*   bucket = cnt + Na;                                // N*BCAP (12.8 MB)
    float* dinv   = (float*)(bucket + (size_t)N * BCAP);     // Na
    unsigned short* A = (unsigned short*)(dinv + Na);        // N*D bf16 (hW)
    float* B = (float*)(A + (((size_t)N * D + 7) & ~(size_t)7)); // N*D fp32 (next h)

    // bucket CSR build: one pass over edges (cnt doubles as cursor)
    hipMemsetAsync(cnt, 0, Na * sizeof(int), stream);
    fill_bucket_kernel<<<(E + 255) / 256, 256, 0, stream>>>(src, dst, cnt, bucket, E);
    dinv_kernel<<<(N + 255) / 256, 256, 0, stream>>>(cnt, dinv, N);

    const int gather_blocks = (N + 7) / 8;
    const float* h = x;
    for (int l = 0; l < 3; ++l) {
        gemm128_kernel<<<(N + TM - 1) / TM, 256, 0, stream>>>(h, Ws[l], A, N);
        float* dest = (l == 2) ? out : B;
        gather_kernel<<<gather_blocks, 256, 0, stream>>>(cnt, bucket, A, dinv,
                                                         bs[l], x, dest, N, l == 2);
        h = B;
    }
}

// Round 6
// 333.373 us; speedup vs baseline: 12.8448x; 1.0288x over previous
//
#include <hip/hip_runtime.h>
#include <hip/hip_bf16.h>

#define D 128
#define BCAP 64          // bucket capacity per node (in-deg Poisson(16); P(>64) ~ 1e-22)
#define TM 64

// ---------------- helpers ----------------

__device__ __forceinline__ unsigned short f2bf_rtne(float f) {
    unsigned int u = __float_as_uint(f);
    u += 0x7fffu + ((u >> 16) & 1u);          // round-to-nearest-even
    return (unsigned short)(u >> 16);
}

__device__ __forceinline__ float bf_lo(unsigned int u) { return __uint_as_float(u << 16); }
__device__ __forceinline__ float bf_hi(unsigned int u) { return __uint_as_float(u & 0xffff0000u); }

// ---------------- shared GEMM tile body: out[n,:] = bf16(h[n,:] @ W) ----------------
// 256 thr, 64 nodes. h staged fp32 in LDS (32 KB) from fp32 or bf16 source.
// Thread: 8 nodes x 4 cols; k-chunks of 4 -> ds_read_b128 + 16 FMA x8.

__device__ __forceinline__ void gemm_tile(const float* __restrict__ h_f32,
                                          const unsigned short* __restrict__ h_bf16,
                                          const float* __restrict__ W,
                                          unsigned short* __restrict__ out,
                                          int n, int tile, float* sh) {
    const int tid = threadIdx.x;
    const int nbase = tile * TM;

    if (h_f32) {
#pragma unroll
        for (int i = 0; i < 8; ++i) {
            int fi = tid + i * 256;
            int node = nbase + (fi >> 5);
            float4 v = make_float4(0.f, 0.f, 0.f, 0.f);
            if (node < n) v = *(const float4*)&h_f32[(size_t)node * D + ((fi & 31) << 2)];
            *(float4*)&sh[fi << 2] = v;
        }
    } else {
#pragma unroll
        for (int i = 0; i < 8; ++i) {
            int fi = tid + i * 256;
            int node = nbase + (fi >> 5);
            float4 v = make_float4(0.f, 0.f, 0.f, 0.f);
            if (node < n) {
                ushort4 u = *(const ushort4*)&h_bf16[(size_t)node * D + ((fi & 31) << 2)];
                v.x = __uint_as_float((unsigned)u.x << 16);
                v.y = __uint_as_float((unsigned)u.y << 16);
                v.z = __uint_as_float((unsigned)u.z << 16);
                v.w = __uint_as_float((unsigned)u.w << 16);
            }
            *(float4*)&sh[fi << 2] = v;
        }
    }
    __syncthreads();

    const int c4 = (tid & 31) << 2;
    const int ng = tid >> 5;
    const float* shb = &sh[(ng * 8) * D];

    float4 acc[8];
#pragma unroll
    for (int j = 0; j < 8; ++j) acc[j] = make_float4(0.f, 0.f, 0.f, 0.f);

    for (int k = 0; k < D; k += 4) {
        float4 w0 = *(const float4*)&W[(size_t)(k + 0) * D + c4];
        float4 w1 = *(const float4*)&W[(size_t)(k + 1) * D + c4];
        float4 w2 = *(const float4*)&W[(size_t)(k + 2) * D + c4];
        float4 w3 = *(const float4*)&W[(size_t)(k + 3) * D + c4];
#pragma unroll
        for (int j = 0; j < 8; ++j) {
            float4 hv = *(const float4*)&shb[j * D + k];   // ds_read_b128
            acc[j].x = fmaf(hv.x, w0.x, acc[j].x); acc[j].y = fmaf(hv.x, w0.y, acc[j].y);
            acc[j].z = fmaf(hv.x, w0.z, acc[j].z); acc[j].w = fmaf(hv.x, w0.w, acc[j].w);
            acc[j].x = fmaf(hv.y, w1.x, acc[j].x); acc[j].y = fmaf(hv.y, w1.y, acc[j].y);
            acc[j].z = fmaf(hv.y, w1.z, acc[j].z); acc[j].w = fmaf(hv.y, w1.w, acc[j].w);
            acc[j].x = fmaf(hv.z, w2.x, acc[j].x); acc[j].y = fmaf(hv.z, w2.y, acc[j].y);
            acc[j].z = fmaf(hv.z, w2.z, acc[j].z); acc[j].w = fmaf(hv.z, w2.w, acc[j].w);
            acc[j].x = fmaf(hv.w, w3.x, acc[j].x); acc[j].y = fmaf(hv.w, w3.y, acc[j].y);
            acc[j].z = fmaf(hv.w, w3.z, acc[j].z); acc[j].w = fmaf(hv.w, w3.w, acc[j].w);
        }
    }

#pragma unroll
    for (int j = 0; j < 8; ++j) {
        int node = nbase + ng * 8 + j;
        if (node < n) {
            ushort4 p;
            p.x = f2bf_rtne(acc[j].x);
            p.y = f2bf_rtne(acc[j].y);
            p.z = f2bf_rtne(acc[j].z);
            p.w = f2bf_rtne(acc[j].w);
            *(ushort4*)&out[(size_t)node * D + c4] = p;
        }
    }
}

// ---------------- fused: gemm0 (x@W0) + bucket fill, interleaved roles ----------------
// gemm0 and the CSR build are independent; fill blocks are latency-bound (VALUBusy
// 0.4%) and co-schedule with gemm's VALU-bound waves (m114-style overlap).

__global__ __launch_bounds__(256) void fused_gemm0_fill_kernel(
        const float* __restrict__ x, const float* __restrict__ W0,
        unsigned short* __restrict__ A,
        const int* __restrict__ src, const int* __restrict__ dst,
        int* __restrict__ cnt, int* __restrict__ bucket,
        int n, int E, int r, int gemmB, int fillB) {
    __shared__ float sh[TM * D];
    int b = blockIdx.x;
    if (b % r == 0) {
        int g = b / r;
        if (g < gemmB) gemm_tile(x, nullptr, W0, A, n, g, sh);
    } else {
        int fid = b - b / r - 1;
        if (fid >= fillB) return;
        int e = fid * 256 + threadIdx.x;
        if (e >= E) return;
        int s = src[e];
        int d = dst[e];
        int pos = atomicAdd(&cnt[d], 1);
        if (pos < BCAP) bucket[((size_t)d << 6) + pos] = s;   // guard: memory-safe
    }
}

__global__ __launch_bounds__(256) void gemm128_kernel(const unsigned short* __restrict__ h,
                                                      const float* __restrict__ W,
                                                      unsigned short* __restrict__ out, int n) {
    __shared__ float sh[TM * D];
    gemm_tile(nullptr, h, W, out, n, blockIdx.x, sh);
}

// ---------------- pull-side aggregation (bf16 rows, bucket CSR), fused epilogue ----
// 32 threads per dst node, 4 features/lane. Edge loop unrolled x8; norms computed
// inline as rsqrt(cnt[s]+1) (broadcast 4B load + cheap VALU; dinv array deleted).
// Inner layers: relu -> bf16 B. Final layer: + x residual -> fp32 out.

__global__ __launch_bounds__(256) void gather_kernel(const int* __restrict__ cnt,
                                                     const int* __restrict__ bucket,
                                                     const unsigned short* __restrict__ hW,
                                                     const float* __restrict__ b,
                                                     const float* __restrict__ x,
                                                     float* __restrict__ out_f32,
                                                     unsigned short* __restrict__ out_bf16,
                                                     int n, int final_layer) {
    int node = blockIdx.x * 8 + (threadIdx.x >> 5);
    if (node >= n) return;
    const int f = (threadIdx.x & 31) << 2;
    const int* row = bucket + ((size_t)node << 6);
    int len = cnt[node];
    float di = rsqrtf((float)len + 1.0f);
    if (len > BCAP) len = BCAP;
    const int len8 = len & ~7;

    float4 acc0 = make_float4(0.f, 0.f, 0.f, 0.f);
    float4 acc1 = make_float4(0.f, 0.f, 0.f, 0.f);
    int k = 0;
    for (; k < len8; k += 8) {
        int4 sa = *(const int4*)&row[k];
        int4 sb = *(const int4*)&row[k + 4];
        float n0 = rsqrtf((float)cnt[sa.x] + 1.0f);
        float n1 = rsqrtf((float)cnt[sa.y] + 1.0f);
        float n2 = rsqrtf((float)cnt[sa.z] + 1.0f);
        float n3 = rsqrtf((float)cnt[sa.w] + 1.0f);
        float n4 = rsqrtf((float)cnt[sb.x] + 1.0f);
        float n5 = rsqrtf((float)cnt[sb.y] + 1.0f);
        float n6 = rsqrtf((float)cnt[sb.z] + 1.0f);
        float n7 = rsqrtf((float)cnt[sb.w] + 1.0f);
        uint2 u0 = *(const uint2*)&hW[(size_t)sa.x * D + f];
        uint2 u1 = *(const uint2*)&hW[(size_t)sa.y * D + f];
        uint2 u2 = *(const uint2*)&hW[(size_t)sa.z * D + f];
        uint2 u3 = *(const uint2*)&hW[(size_t)sa.w * D + f];
        uint2 u4 = *(const uint2*)&hW[(size_t)sb.x * D + f];
        uint2 u5 = *(const uint2*)&hW[(size_t)sb.y * D + f];
        uint2 u6 = *(const uint2*)&hW[(size_t)sb.z * D + f];
        uint2 u7 = *(const uint2*)&hW[(size_t)sb.w * D + f];
        acc0.x = fmaf(bf_lo(u0.x), n0, acc0.x); acc0.y = fmaf(bf_hi(u0.x), n0, acc0.y);
        acc0.z = fmaf(bf_lo(u0.y), n0, acc0.z); acc0.w = fmaf(bf_hi(u0.y), n0, acc0.w);
        acc1.x = fmaf(bf_lo(u1.x), n1, acc1.x); acc1.y = fmaf(bf_hi(u1.x), n1, acc1.y);
        acc1.z = fmaf(bf_lo(u1.y), n1, acc1.z); acc1.w = fmaf(bf_hi(u1.y), n1, acc1.w);
        acc0.x = fmaf(bf_lo(u2.x), n2, acc0.x); acc0.y = fmaf(bf_hi(u2.x), n2, acc0.y);
        acc0.z = fmaf(bf_lo(u2.y), n2, acc0.z); acc0.w = fmaf(bf_hi(u2.y), n2, acc0.w);
        acc1.x = fmaf(bf_lo(u3.x), n3, acc1.x); acc1.y = fmaf(bf_hi(u3.x), n3, acc1.y);
        acc1.z = fmaf(bf_lo(u3.y), n3, acc1.z); acc1.w = fmaf(bf_hi(u3.y), n3, acc1.w);
        acc0.x = fmaf(bf_lo(u4.x), n4, acc0.x); acc0.y = fmaf(bf_hi(u4.x), n4, acc0.y);
        acc0.z = fmaf(bf_lo(u4.y), n4, acc0.z); acc0.w = fmaf(bf_hi(u4.y), n4, acc0.w);
        acc1.x = fmaf(bf_lo(u5.x), n5, acc1.x); acc1.y = fmaf(bf_hi(u5.x), n5, acc1.y);
        acc1.z = fmaf(bf_lo(u5.y), n5, acc1.z); acc1.w = fmaf(bf_hi(u5.y), n5, acc1.w);
        acc0.x = fmaf(bf_lo(u6.x), n6, acc0.x); acc0.y = fmaf(bf_hi(u6.x), n6, acc0.y);
        acc0.z = fmaf(bf_lo(u6.y), n6, acc0.z); acc0.w = fmaf(bf_hi(u6.y), n6, acc0.w);
        acc1.x = fmaf(bf_lo(u7.x), n7, acc1.x); acc1.y = fmaf(bf_hi(u7.x), n7, acc1.y);
        acc1.z = fmaf(bf_lo(u7.y), n7, acc1.z); acc1.w = fmaf(bf_hi(u7.y), n7, acc1.w);
    }
    for (; k < len; ++k) {
        int s = row[k];
        float ns = rsqrtf((float)cnt[s] + 1.0f);
        uint2 u = *(const uint2*)&hW[(size_t)s * D + f];
        acc0.x = fmaf(bf_lo(u.x), ns, acc0.x); acc0.y = fmaf(bf_hi(u.x), ns, acc0.y);
        acc0.z = fmaf(bf_lo(u.y), ns, acc0.z); acc0.w = fmaf(bf_hi(u.y), ns, acc0.w);
    }

    uint2 uh = *(const uint2*)&hW[(size_t)node * D + f];
    float4 acc;
    acc.x = fmaf(bf_lo(uh.x), di, acc0.x + acc1.x);
    acc.y = fmaf(bf_hi(uh.x), di, acc0.y + acc1.y);
    acc.z = fmaf(bf_lo(uh.y), di, acc0.z + acc1.z);
    acc.w = fmaf(bf_hi(uh.y), di, acc0.w + acc1.w);

    float4 bv = *(const float4*)&b[f];
    float4 r;
    r.x = fmaf(acc.x, di, bv.x);
    r.y = fmaf(acc.y, di, bv.y);
    r.z = fmaf(acc.z, di, bv.z);
    r.w = fmaf(acc.w, di, bv.w);

    if (final_layer) {
        float4 xv = *(const float4*)&x[(size_t)node * D + f];
        r.x += xv.x; r.y += xv.y; r.z += xv.z; r.w += xv.w;
        *(float4*)&out_f32[(size_t)node * D + f] = r;
    } else {
        ushort4 p;
        p.x = f2bf_rtne(fmaxf(r.x, 0.f));
        p.y = f2bf_rtne(fmaxf(r.y, 0.f));
        p.z = f2bf_rtne(fmaxf(r.z, 0.f));
        p.w = f2bf_rtne(fmaxf(r.w, 0.f));
        *(ushort4*)&out_bf16[(size_t)node * D + f] = p;
    }
}

// ---------------- launch ----------------

extern "C" void kernel_launch(void* const* d_in, const int* in_sizes, int n_in,
                              void* d_out, int out_size, void* d_ws, size_t ws_size,
                              hipStream_t stream) {
    const float* x  = (const float*)d_in[0];
    const int*   ei = (const int*)d_in[1];
    const float* Ws[3] = {(const float*)d_in[2], (const float*)d_in[4], (const float*)d_in[6]};
    const float* bs[3] = {(const float*)d_in[3], (const float*)d_in[5], (const float*)d_in[7]};
    float* out = (float*)d_out;

    const int N = in_sizes[0] / D;
    const int E = in_sizes[1] / 2;
    const int* src = ei;
    const int* dst = ei + E;

    // workspace layout (16B-aligned pieces)
    const size_t Na = ((size_t)N + 3) & ~(size_t)3;
    int* cnt    = (int*)d_ws;                                // Na
    int* bucket = cnt + Na;                                  // N*BCAP (12.8 MB)
    unsigned short* A = (unsigned short*)(bucket + (size_t)N * BCAP);  // N*D bf16 (hW)
    unsigned short* B = A + (((size_t)N * D + 7) & ~(size_t)7);        // N*D bf16 (next h)

    const int gemmB = (N + TM - 1) / TM;
    const int fillB = (E + 255) / 256;
    const int r = 1 + (fillB + gemmB - 1) / gemmB;           // interleave stride
    const int fusedGrid = gemmB * r;

    hipMemsetAsync(cnt, 0, Na * sizeof(int), stream);
    // layer 0 GEMM + bucket CSR build, overlapped in one dispatch
    fused_gemm0_fill_kernel<<<fusedGrid, 256, 0, stream>>>(x, Ws[0], A, src, dst,
                                                           cnt, bucket, N, E, r, gemmB, fillB);

    const int gather_blocks = (N + 7) / 8;
    for (int l = 0; l < 3; ++l) {
        if (l > 0) {
            gemm128_kernel<<<gemmB, 256, 0, stream>>>(B, Ws[l], A, N);
        }
        gather_kernel<<<gather_blocks, 256, 0, stream>>>(cnt, bucket, A, bs[l], x,
                                                         out, B, N, l == 2);
    }
}